// Round 5
// baseline (1213.640 us; speedup 1.0000x reference)
//
#include <hip/hip_runtime.h>
#include <hip/hip_bf16.h>

// Problem constants
#define B_      4
#define CIN     128
#define HW_     256      // H == W
#define L_      65536    // H*W
#define CO      16       // conv out channels per input
#define D_      32       // token dim

// ---- workspace layout (float offsets) ----
#define BIAS_OFF  0          // 4*64*64 rel-pos bias, packed [j(key)][i(query)][h] -> float4 per (j,i)
#define QKVW_OFF  16384      // 96*32
#define QKVB_OFF  19456      // 96
#define PROJW_OFF 19552      // 32*32
#define PROJB_OFF 20576      // 32
#define N1G_OFF   20608
#define N1B_OFF   20640
#define N2G_OFF   20672
#define N2B_OFF   20704
#define FC1W_OFF  20736      // 128*32
#define FC1B_OFF  24832      // 128
#define FC2T_OFF  24960      // 128*32, transposed to [i][c]
#define FC2B_OFF  29056      // 32
#define PREP_N    29088
#define MODE_OFF  29088      // int: 1 = bf16 tensors, 0 = f32 tensors

// ---- dtype helpers ----
__device__ __forceinline__ float to_f(float v) { return v; }
__device__ __forceinline__ float to_f(__hip_bfloat16 v) { return __bfloat162float(v); }
__device__ __forceinline__ void st_f(float* p, size_t i, float v) { p[i] = v; }
__device__ __forceinline__ void st_f(__hip_bfloat16* p, size_t i, float v) { p[i] = __float2bfloat16(v); }

// broadcast value from lane j (uniform j) -- pure VALU, no LDS
__device__ __forceinline__ float rl(float v, int j) {
    return __int_as_float(__builtin_amdgcn_readlane(__float_as_int(v), j));
}

// ============================ K-1: dtype detect ============================
__global__ void detect_kernel(const __hip_bfloat16* __restrict__ in0, int* __restrict__ flag) {
    __shared__ int bad;
    if (threadIdx.x == 0) bad = 0;
    __syncthreads();
    int cnt = 0;
    for (int k = 0; k < 32; k++) {
        float v = __bfloat162float(in0[threadIdx.x + k * 256]);
        if (!(fabsf(v) < 1e8f)) cnt++;   // catches huge AND NaN
    }
    if (cnt) atomicAdd(&bad, cnt);
    __syncthreads();
    if (threadIdx.x == 0) *flag = (bad > 32) ? 0 : 1;
}

// ============================ K0: weight prep ============================
template <typename T>
__device__ void prep_impl(const T* qkv_w, const T* qkv_b, const T* rpb, const T* proj_w,
                          const T* proj_b, const T* n1g, const T* n1b, const T* n2g,
                          const T* n2b, const T* fc1_w, const T* fc1_b, const T* fc2_w,
                          const T* fc2_b, float* ws, int idx) {
    if (idx < 16384) {
        // bias packed as float4 per (j,i): ws[BIAS_OFF + (j*64+i)*4 + h]
        int h = idx & 3;
        int i = (idx >> 2) & 63;
        int j = idx >> 8;
        int dy = (i >> 3) - (j >> 3) + 7;
        int dx = (i & 7) - (j & 7) + 7;
        ws[BIAS_OFF + idx] = to_f(rpb[(dy * 15 + dx) * 4 + h]);
        return;
    }
    int t = idx - 16384;
    if (t < 3072) { ws[QKVW_OFF + t] = to_f(qkv_w[t]); return; }
    t -= 3072;
    if (t < 96)   { ws[QKVB_OFF + t] = to_f(qkv_b[t]); return; }
    t -= 96;
    if (t < 1024) { ws[PROJW_OFF + t] = to_f(proj_w[t]); return; }
    t -= 1024;
    if (t < 32)   { ws[PROJB_OFF + t] = to_f(proj_b[t]); return; }
    t -= 32;
    if (t < 128) {
        int which = t >> 5, ln = t & 31;
        const T* src = (which == 0) ? n1g : (which == 1) ? n1b : (which == 2) ? n2g : n2b;
        int off = (which == 0) ? N1G_OFF : (which == 1) ? N1B_OFF : (which == 2) ? N2G_OFF : N2B_OFF;
        ws[off + ln] = to_f(src[ln]);
        return;
    }
    t -= 128;
    if (t < 4096) { ws[FC1W_OFF + t] = to_f(fc1_w[t]); return; }
    t -= 4096;
    if (t < 128)  { ws[FC1B_OFF + t] = to_f(fc1_b[t]); return; }
    t -= 128;
    if (t < 4096) {  // fc2_w (32,128) -> fc2t[i*32+c]
        int i = t >> 5, c = t & 31;
        ws[FC2T_OFF + t] = to_f(fc2_w[c * 128 + i]);
        return;
    }
    t -= 4096;
    ws[FC2B_OFF + t] = to_f(fc2_b[t]);
}

__global__ void prep_kernel(const void* qkv_w, const void* qkv_b, const void* rpb,
                            const void* proj_w, const void* proj_b,
                            const void* n1g, const void* n1b, const void* n2g, const void* n2b,
                            const void* fc1_w, const void* fc1_b, const void* fc2_w, const void* fc2_b,
                            float* __restrict__ ws) {
    int idx = blockIdx.x * 256 + threadIdx.x;
    if (idx >= PREP_N) return;
    const int mode = *(const int*)(ws + MODE_OFF);
    if (mode) {
        prep_impl<__hip_bfloat16>((const __hip_bfloat16*)qkv_w, (const __hip_bfloat16*)qkv_b,
            (const __hip_bfloat16*)rpb, (const __hip_bfloat16*)proj_w, (const __hip_bfloat16*)proj_b,
            (const __hip_bfloat16*)n1g, (const __hip_bfloat16*)n1b, (const __hip_bfloat16*)n2g,
            (const __hip_bfloat16*)n2b, (const __hip_bfloat16*)fc1_w, (const __hip_bfloat16*)fc1_b,
            (const __hip_bfloat16*)fc2_w, (const __hip_bfloat16*)fc2_b, ws, idx);
    } else {
        prep_impl<float>((const float*)qkv_w, (const float*)qkv_b, (const float*)rpb,
            (const float*)proj_w, (const float*)proj_b, (const float*)n1g, (const float*)n1b,
            (const float*)n2g, (const float*)n2b, (const float*)fc1_w, (const float*)fc1_b,
            (const float*)fc2_w, (const float*)fc2_b, ws, idx);
    }
}

// ============================ K1: dual conv3x3 ============================
// Software-pipelined ci loop: taps for ci+1 are loaded into the other buffer
// BEFORE computing ci, so the 18 global loads hide under 288 FMAs.
#define LTAPS(VI, VE, CI) do {                                                  \
    const T* ip_ = ibase + (size_t)(CI) * L_;                                   \
    const T* ep_ = ebase + (size_t)(CI) * L_;                                   \
    _Pragma("unroll")                                                           \
    for (int rr = 0; rr < 3; rr++) {                                            \
        int hh_ = h + rr - 1;                                                   \
        bool vh_ = ((unsigned)hh_ < 256u);                                      \
        int roff_ = (rr - 1) * 256;                                             \
        _Pragma("unroll")                                                       \
        for (int cc = 0; cc < 3; cc++) {                                        \
            int wwp_ = w + cc - 1;                                              \
            bool ok_ = vh_ && ((unsigned)wwp_ < 256u);                          \
            int off_ = roff_ + (cc - 1);                                        \
            VI[rr * 3 + cc] = ok_ ? to_f(ip_[off_]) : 0.0f;                     \
            VE[rr * 3 + cc] = ok_ ? to_f(ep_[off_]) : 0.0f;                     \
        }                                                                       \
    }                                                                           \
} while (0)

#define CTAPS(VI, VE, CI) do {                                                  \
    const float4* wrow_ = (const float4*)&wlds[(CI) * 144];                     \
    _Pragma("unroll")                                                           \
    for (int tap = 0; tap < 9; tap++) {                                         \
        float a_ = VI[tap], e2_ = VE[tap];                                      \
        _Pragma("unroll")                                                       \
        for (int q4 = 0; q4 < 4; q4++) {                                        \
            float4 wv_ = wrow_[tap * 4 + q4];                                   \
            accI[q4 * 4 + 0] += a_ * wv_.x;  accE[q4 * 4 + 0] += e2_ * wv_.x;   \
            accI[q4 * 4 + 1] += a_ * wv_.y;  accE[q4 * 4 + 1] += e2_ * wv_.y;   \
            accI[q4 * 4 + 2] += a_ * wv_.z;  accE[q4 * 4 + 2] += e2_ * wv_.z;   \
            accI[q4 * 4 + 3] += a_ * wv_.w;  accE[q4 * 4 + 3] += e2_ * wv_.w;   \
        }                                                                       \
    }                                                                           \
} while (0)

template <typename T>
__device__ void conv_impl(const T* __restrict__ img, const T* __restrict__ evt,
                          const T* __restrict__ cw, const T* __restrict__ cb,
                          T* __restrict__ out, float* wlds) {
    const int tid = threadIdx.x;
    const int b = blockIdx.x >> 8;
    const int h = blockIdx.x & 255;
    const int w = tid;

    float accI[16], accE[16];
#pragma unroll
    for (int c = 0; c < 16; c++) {
        float bb = to_f(cb[c]);
        accI[c] = bb; accE[c] = bb;
    }

    for (int chunk = 0; chunk < 2; chunk++) {
        const int ci0 = chunk * 64;
        __syncthreads();
        // stage 64ci x 9tap x 16co weights, transposed, ->f32
        for (int k = 0; k < 36; k++) {
            int flat = tid + k * 256;                 // < 9216
            int ci_l = flat / 144;
            int rem = flat - ci_l * 144;              // tap*16 + co
            int tap = rem >> 4; int co = rem & 15;
            wlds[flat] = to_f(cw[(co * CIN + ci0 + ci_l) * 9 + tap]);
        }
        __syncthreads();

        const T* ibase = img + ((size_t)(b * CIN + ci0) * HW_ + h) * HW_ + w;
        const T* ebase = evt + ((size_t)(b * CIN + ci0) * HW_ + h) * HW_ + w;

        float viA[9], veA[9], viB[9], veB[9];
        LTAPS(viA, veA, 0);
        for (int ci = 0; ci < 64; ci += 2) {
            LTAPS(viB, veB, ci + 1);              // prefetch odd while computing even
            CTAPS(viA, veA, ci);
            if (ci + 2 < 64) LTAPS(viA, veA, ci + 2);  // prefetch next even
            CTAPS(viB, veB, ci + 1);
        }
    }

    // NCHW stores; per-c the 256 lanes (w) are contiguous -> coalesced
    const size_t l = (size_t)(h << 8) + w;
#pragma unroll
    for (int c = 0; c < 16; c++) {
        st_f(out, (((size_t)(b * 32 + c)) << 16) + l, accI[c]);
        st_f(out, (((size_t)(b * 32 + 16 + c)) << 16) + l, accE[c]);
    }
}

__global__ __launch_bounds__(256) void conv_kernel(const void* img, const void* evt,
                                                   const void* cw, const void* cb,
                                                   void* out, const float* __restrict__ ws) {
    __shared__ float wlds[64 * 9 * 16];  // 36.9 KB
    const int mode = *(const int*)(ws + MODE_OFF);
    if (mode) {
        conv_impl<__hip_bfloat16>((const __hip_bfloat16*)img, (const __hip_bfloat16*)evt,
            (const __hip_bfloat16*)cw, (const __hip_bfloat16*)cb, (__hip_bfloat16*)out, wlds);
    } else {
        conv_impl<float>((const float*)img, (const float*)evt,
            (const float*)cw, (const float*)cb, (float*)out, wlds);
    }
}

// ============================ K2: fused window block ============================
// One wave per 8x8 window. Thread = token.
//  - Only V lives in LDS (9216 B).
//  - K in registers; row j broadcast via v_readlane (pure VALU).
//  - Liveness-shaped schedule (round-4 fix): compute Q/K for heads 0-1 only,
//    run pass 1 (y[32] stays live), THEN compute Q/K for heads 2-3 from y
//    (y dies) and run pass 2. Peak live ~85 regs vs ~135 when all 4 heads'
//    Q/K were built up front (which pinned VGPR at 128 and spilled ~95 MB).
//    sched_barrier(0) stops the scheduler from hoisting the heads-2-3 build
//    back above pass 1.
//  - no-max softmax (scores O(10); exp overflows at 88).
template <int HB>
__device__ __forceinline__ void attn_pass(const float* __restrict__ ws, const float* __restrict__ v_lds,
                                          const float* qv2, const float* kv2, int i, float* ao) {
    float acc[16];
#pragma unroll
    for (int e = 0; e < 16; e++) acc[e] = 0.f;
    float l0 = 0.f, l1 = 0.f;

#pragma unroll 2
    for (int j = 0; j < 64; j++) {
        // bias floats for heads HB/8, HB/8+1 at packed [j][i][h]
        float2 bj = *(const float2*)&ws[BIAS_OFF + ((j * 64 + i) << 2) + (HB >> 3)];
        float s0 = bj.x, s1 = bj.y;
#pragma unroll
        for (int e = 0; e < 8; e++) {
            s0 += qv2[e]     * rl(kv2[e], j);
            s1 += qv2[8 + e] * rl(kv2[8 + e], j);
        }
        float p0 = __expf(s0), p1 = __expf(s1);
        l0 += p0; l1 += p1;

        const float4* vp = (const float4*)&v_lds[j * 36 + HB];
        float4 v0 = vp[0], v1 = vp[1], v2 = vp[2], v3 = vp[3];
        acc[0]  += p0 * v0.x;  acc[1]  += p0 * v0.y;  acc[2]  += p0 * v0.z;  acc[3]  += p0 * v0.w;
        acc[4]  += p0 * v1.x;  acc[5]  += p0 * v1.y;  acc[6]  += p0 * v1.z;  acc[7]  += p0 * v1.w;
        acc[8]  += p1 * v2.x;  acc[9]  += p1 * v2.y;  acc[10] += p1 * v2.z;  acc[11] += p1 * v2.w;
        acc[12] += p1 * v3.x;  acc[13] += p1 * v3.y;  acc[14] += p1 * v3.z;  acc[15] += p1 * v3.w;
    }
    float i0 = 1.0f / l0, i1 = 1.0f / l1;
#pragma unroll
    for (int e = 0; e < 8; e++) {
        ao[HB + e]     = acc[e]     * i0;
        ao[HB + 8 + e] = acc[8 + e] * i1;
    }
}

template <typename T>
__device__ void fused_impl(const float* __restrict__ ws, T* __restrict__ out,
                           float* v_lds) {
    const int i = threadIdx.x;
    const int wid = blockIdx.x;
    const int b = wid >> 10;
    const int r = wid & 1023;
    const int wy = r >> 5, wx = r & 31;
    const int ty = i >> 3, tx = i & 7;
    const size_t l = (size_t)(((wy * 8 + ty) << 8) + (wx * 8 + tx));
    const size_t cbase = ((size_t)(b * 32)) << 16;

    // ---- LN1 (xv consumed into y; reloaded later for the residual) ----
    float y[32];
    {
        float xv[32];
#pragma unroll
        for (int c = 0; c < 32; c++)
            xv[c] = to_f(out[cbase + (((size_t)c) << 16) + l]);
        float mu = 0.f;
#pragma unroll
        for (int d = 0; d < 32; d++) mu += xv[d];
        mu *= (1.0f / 32.0f);
        float var = 0.f;
#pragma unroll
        for (int d = 0; d < 32; d++) { float dl = xv[d] - mu; var += dl * dl; }
        var *= (1.0f / 32.0f);
        float rstd = rsqrtf(var + 1e-5f);
#pragma unroll
        for (int d = 0; d < 32; d++)
            y[d] = (xv[d] - mu) * rstd * ws[N1G_OFF + d] + ws[N1B_OFF + d];
    }

    const float4* qw = (const float4*)(ws + QKVW_OFF);
    const float* qb = ws + QKVB_OFF;
    const float scale = 0.35355339059327373f;  // 8^-0.5

    // ---- V -> LDS (frees its temporaries before Q/K live) ----
    for (int og = 0; og < 8; og++) {
        float s4[4];
#pragma unroll
        for (int q = 0; q < 4; q++) {
            float s = qb[64 + og * 4 + q];
#pragma unroll
            for (int d4 = 0; d4 < 8; d4++) {
                float4 wv = qw[(64 + og * 4 + q) * 8 + d4];
                s += wv.x * y[d4 * 4] + wv.y * y[d4 * 4 + 1] + wv.z * y[d4 * 4 + 2] + wv.w * y[d4 * 4 + 3];
            }
            s4[q] = s;
        }
        *(float4*)&v_lds[i * 36 + og * 4] = make_float4(s4[0], s4[1], s4[2], s4[3]);
    }

    // ---- Q/K for heads 0,1 only ----
    float qv01[16], kv01[16];
#pragma unroll
    for (int o = 0; o < 16; o++) {
        float s = qb[o];
#pragma unroll
        for (int d4 = 0; d4 < 8; d4++) {
            float4 wv = qw[o * 8 + d4];
            s += wv.x * y[d4 * 4] + wv.y * y[d4 * 4 + 1] + wv.z * y[d4 * 4 + 2] + wv.w * y[d4 * 4 + 3];
        }
        qv01[o] = s * scale;
    }
#pragma unroll
    for (int o = 0; o < 16; o++) {
        float s = qb[32 + o];
#pragma unroll
        for (int d4 = 0; d4 < 8; d4++) {
            float4 wv = qw[(32 + o) * 8 + d4];
            s += wv.x * y[d4 * 4] + wv.y * y[d4 * 4 + 1] + wv.z * y[d4 * 4 + 2] + wv.w * y[d4 * 4 + 3];
        }
        kv01[o] = s;
    }
    __syncthreads();

    float ao[32];
    attn_pass<0>(ws, v_lds, qv01, kv01, i, ao);

    // keep the heads-2-3 Q/K build AFTER pass 1 (liveness shaping)
    __builtin_amdgcn_sched_barrier(0);

    // ---- Q/K for heads 2,3 (y dies here) ----
    float qv23[16], kv23[16];
#pragma unroll
    for (int o = 0; o < 16; o++) {
        float s = qb[16 + o];
#pragma unroll
        for (int d4 = 0; d4 < 8; d4++) {
            float4 wv = qw[(16 + o) * 8 + d4];
            s += wv.x * y[d4 * 4] + wv.y * y[d4 * 4 + 1] + wv.z * y[d4 * 4 + 2] + wv.w * y[d4 * 4 + 3];
        }
        qv23[o] = s * scale;
    }
#pragma unroll
    for (int o = 0; o < 16; o++) {
        float s = qb[48 + o];
#pragma unroll
        for (int d4 = 0; d4 < 8; d4++) {
            float4 wv = qw[(48 + o) * 8 + d4];
            s += wv.x * y[d4 * 4] + wv.y * y[d4 * 4 + 1] + wv.z * y[d4 * 4 + 2] + wv.w * y[d4 * 4 + 3];
        }
        kv23[o] = s;
    }

    attn_pass<16>(ws, v_lds, qv23, kv23, i, ao);

    // ---- reload xv (L2-hot), proj + residual -> xres ----
    float xv[32];
#pragma unroll
    for (int c = 0; c < 32; c++)
        xv[c] = to_f(out[cbase + (((size_t)c) << 16) + l]);

    const float4* pw = (const float4*)(ws + PROJW_OFF);
    float xres[32];
#pragma unroll
    for (int c = 0; c < 32; c++) {
        float s = ws[PROJB_OFF + c];
#pragma unroll
        for (int d4 = 0; d4 < 8; d4++) {
            float4 wv = pw[c * 8 + d4];
            s += wv.x * ao[d4 * 4] + wv.y * ao[d4 * 4 + 1] + wv.z * ao[d4 * 4 + 2] + wv.w * ao[d4 * 4 + 3];
        }
        xres[c] = xv[c] + s;
    }

    // ---- LayerNorm 2 ----
    float mu = 0.f;
#pragma unroll
    for (int d = 0; d < 32; d++) mu += xres[d];
    mu *= (1.0f / 32.0f);
    float var = 0.f;
#pragma unroll
    for (int d = 0; d < 32; d++) { float dl = xres[d] - mu; var += dl * dl; }
    var *= (1.0f / 32.0f);
    float rstd = rsqrtf(var + 1e-5f);
    float y2[32];
#pragma unroll
    for (int d = 0; d < 32; d++)
        y2[d] = (xres[d] - mu) * rstd * ws[N2G_OFF + d] + ws[N2B_OFF + d];

    // ---- MLP: fc1 -> exact GELU -> fc2 ----
    float outv[32];
#pragma unroll
    for (int c = 0; c < 32; c++) outv[c] = ws[FC2B_OFF + c];

    const float4* w1 = (const float4*)(ws + FC1W_OFF);
    const float4* w2t = (const float4*)(ws + FC2T_OFF);
    const float* b1 = ws + FC1B_OFF;
#pragma unroll 4
    for (int ii = 0; ii < 128; ii++) {
        float s = b1[ii];
#pragma unroll
        for (int d4 = 0; d4 < 8; d4++) {
            float4 wv = w1[ii * 8 + d4];
            s += wv.x * y2[d4 * 4] + wv.y * y2[d4 * 4 + 1] + wv.z * y2[d4 * 4 + 2] + wv.w * y2[d4 * 4 + 3];
        }
        float g = 0.5f * s * (1.0f + erff(s * 0.7071067811865475f));
#pragma unroll
        for (int c4 = 0; c4 < 8; c4++) {
            float4 wv = w2t[ii * 8 + c4];
            outv[c4 * 4 + 0] += g * wv.x;  outv[c4 * 4 + 1] += g * wv.y;
            outv[c4 * 4 + 2] += g * wv.z;  outv[c4 * 4 + 3] += g * wv.w;
        }
    }

    // ---- final residual + store to the SAME addresses this thread read ----
#pragma unroll
    for (int c = 0; c < 32; c++) {
        st_f(out, cbase + (((size_t)c) << 16) + l, xres[c] + outv[c]);
    }
}

__global__ __launch_bounds__(64, 2) void fused_kernel(const float* __restrict__ ws, void* out) {
    __shared__ float v_lds[64 * 36];   // 9216 B
    const int mode = *(const int*)(ws + MODE_OFF);
    if (mode) fused_impl<__hip_bfloat16>(ws, (__hip_bfloat16*)out, v_lds);
    else      fused_impl<float>(ws, (float*)out, v_lds);
}

// ============================ launch ============================
extern "C" void kernel_launch(void* const* d_in, const int* in_sizes, int n_in,
                              void* d_out, int out_size, void* d_ws, size_t ws_size,
                              hipStream_t stream) {
    float* ws = (float*)d_ws;
    int* mode_flag = (int*)(ws + MODE_OFF);

    hipLaunchKernelGGL(detect_kernel, dim3(1), dim3(256), 0, stream,
                       (const __hip_bfloat16*)d_in[0], mode_flag);
    hipLaunchKernelGGL(prep_kernel, dim3((PREP_N + 255) / 256), dim3(256), 0, stream,
                       d_in[6], d_in[7], d_in[8], d_in[9], d_in[10],
                       d_in[4], d_in[5], d_in[11], d_in[12],
                       d_in[13], d_in[14], d_in[15], d_in[16], ws);
    hipLaunchKernelGGL(conv_kernel, dim3(B_ * HW_), dim3(256), 0, stream,
                       d_in[0], d_in[1], d_in[2], d_in[3], d_out, (const float*)ws);
    hipLaunchKernelGGL(fused_kernel, dim3(4096), dim3(64), 0, stream, (const float*)ws, d_out);
}